// Round 14
// baseline (188.827 us; speedup 1.0000x reference)
//
#include <hip/hip_runtime.h>

// Involution: out[b, g*64+c, ho, wo] = sum_{kh,kw} xp[b, g*64+c, ho+kh, wo+kw] * W[b,g,kh,kw,ho,wo]
// B=8, C=512, G=8, cpg=64, H=W=Ho=Wo=64, K=7, PAD=3. fp32.
//
// R15: occupancy bump in the stall-free regime. R14 (75.5us, new best):
// VGPR 116 no-spill, weight stalls gone, but Occupancy 19.5% with LDS pipe
// ~45% / VALU ~38% -- both unsaturated, overlap-able across waves; blocks
// too big (50688B LDS -> 3/CU cap) and grid only 8 blocks/CU of work.
// Unlike R9 (occupancy-null), the serial weight-stall is gone and the open
// register budget is kept -- TLP should convert now.
// Change: CHPC 8->4, CSPLIT 8->16 (grid 4096). LDS 25344B; ~4 blocks/CU
// resident (16 waves, waves_per_eu(2,4) cap). Everything else = R14:
// quad-split mod-4 LDS layout (4px/thread, 10 b32 reads per ch,kh),
// kh-double-buffered float4 weights, XCD swizzle, register staging.
// Predict: occ 19.5->40-50, dur 75.5->58-68; flat => per-wave latency
// bound -> attack read2 conflict pattern (10.5M, ~17us LDS-pipe) next.
// Tripwire: FETCH/WRITE balloon = spill (abort).

#define BB 8
#define CC 512
#define GG 8
#define CPG 64
#define HH 64
#define WW 64
#define HW (HH * WW)
#define KK 7
#define PAD 3

#define TILE_ROWS 16
#define CSPLIT 16
#define CHPC 4                            // channels per block
#define LDS_ROWS (TILE_ROWS + KK - 1)     // 22
#define LDS_PITCH 72                      // 4 quarters x 18 words
#define QUARTER 18
#define CH_STRIDE (LDS_ROWS * LDS_PITCH)  // 1584 words per channel plane
#define PLANE_QUADS (LDS_ROWS * 18)       // 396 staging quads per plane
#define TOT_QUADS (CHPC * PLANE_QUADS)    // 1584
#define NPASS 7                           // ceil(1584/256)

__global__ __launch_bounds__(256)
__attribute__((amdgpu_waves_per_eu(2, 4)))
void involution_kernel(const float* __restrict__ x,
                       const float* __restrict__ weight,
                       float* __restrict__ out) {
    const int tid = threadIdx.x;
    const int tx = tid & 15;          // wo0 = 4*tx
    const int ty = tid >> 4;          // 0..15, row within tile

    // ---- XCD-locality decode: all 64 sub-blocks of a (b,g) on one XCD ----
    const int f = blockIdx.x;         // 0..4095
    const int xcd = f & 7;
    const int k = f >> 3;             // 0..511
    const int bg = ((k >> 6) << 3) + xcd;   // 0..63, bijective
    const int sub = k & 63;           // 0..63
    const int b = bg >> 3;
    const int g = bg & 7;
    const int tile = sub >> 4;        // 0..3
    const int cs = sub & 15;          // 0..15

    const int wo0 = tx << 2;
    const int hbase = tile * TILE_ROWS;
    const int ho = hbase + ty;

    __shared__ float xs[CHPC * CH_STRIDE];   // 25344 B

    // per-pixel weight base: tap t at +t*HW; float4 covers wo0..wo0+3
    const float* wq = weight + ((size_t)(b * GG + g) * (KK * KK)) * HW
                    + ho * WW + wo0;

    const size_t cbase = (size_t)(b * CC + g * CPG + cs * CHPC) * HW;
    const float* xg = x + cbase;
    float* og = out + cbase + ho * WW + wo0;

    // ---- staging: 1584 quads in 7 masked passes; quad-split LDS writes ----
    float4 sv[NPASS];
    int lofs[NPASS];
    bool act[NPASS];
#pragma unroll
    for (int i = 0; i < NPASS; ++i) {
        const int Q = tid + i * 256;
        act[i] = (Q < TOT_QUADS);
        const int ch = Q / PLANE_QUADS;
        const int rem = Q - ch * PLANE_QUADS;
        const int sr = rem / 18;              // 0..21
        const int sq = rem - sr * 18;         // 0..17
        const int xrow = hbase + sr - PAD;    // -3..66
        const int xcol = (sq << 2) - 4;       // -4..64 (pc = 4*sq + ii)
        const bool ld = act[i]
                     && ((unsigned)xrow < HH) && ((unsigned)xcol < WW);
        float4 v = make_float4(0.f, 0.f, 0.f, 0.f);
        if (ld)
            v = *(const float4*)(xg + (size_t)ch * HW + xrow * WW + xcol);
        sv[i] = v;
        lofs[i] = ch * CH_STRIDE + sr * LDS_PITCH + sq;
    }

    // ---- kh=0 weight taps (latency hides under LDS writes + barrier) ----
    float4 wka[KK], wkb[KK];
#pragma unroll
    for (int j = 0; j < KK; ++j)
        wka[j] = *(const float4*)(wq + (size_t)j * HW);

#pragma unroll
    for (int i = 0; i < NPASS; ++i) {
        if (act[i]) {
            xs[lofs[i]]               = sv[i].x;   // pc%4==0 quarter
            xs[lofs[i] + QUARTER]     = sv[i].y;
            xs[lofs[i] + 2 * QUARTER] = sv[i].z;
            xs[lofs[i] + 3 * QUARTER] = sv[i].w;
        }
    }
    __syncthreads();                 // planes visible

    // ---- compute: kh unrolled, weights double-buffered, 4 px/thread ----
    float4 acc[CHPC];
#pragma unroll
    for (int ch = 0; ch < CHPC; ++ch)
        acc[ch] = make_float4(0.f, 0.f, 0.f, 0.f);

    // v[d] = x at pc = 4tx+1+d ; pixel p tap j uses v[p+j]
#define KH_STEP(KH, WCUR, WNXT, NKH, LN)                                    \
    {                                                                       \
        if (LN) {                                                           \
            _Pragma("unroll")                                               \
            for (int j = 0; j < KK; ++j)                                    \
                WNXT[j] = *(const float4*)(wq + (size_t)((NKH) * KK + j) * HW); \
        }                                                                   \
        _Pragma("unroll")                                                   \
        for (int ch = 0; ch < CHPC; ++ch) {                                 \
            const int b2 = ch * CH_STRIDE + (ty + (KH)) * LDS_PITCH;        \
            const float v0 = xs[b2 + QUARTER + tx];                         \
            const float v1 = xs[b2 + 2 * QUARTER + tx];                     \
            const float v2 = xs[b2 + 3 * QUARTER + tx];                     \
            const float v3 = xs[b2 + tx + 1];                               \
            const float v4 = xs[b2 + QUARTER + tx + 1];                     \
            const float v5 = xs[b2 + 2 * QUARTER + tx + 1];                 \
            const float v6 = xs[b2 + 3 * QUARTER + tx + 1];                 \
            const float v7 = xs[b2 + tx + 2];                               \
            const float v8 = xs[b2 + QUARTER + tx + 2];                     \
            const float v9 = xs[b2 + 2 * QUARTER + tx + 2];                 \
            float4 a = acc[ch];                                             \
            a.x = fmaf(v0, WCUR[0].x, a.x);  a.y = fmaf(v1, WCUR[0].y, a.y); \
            a.z = fmaf(v2, WCUR[0].z, a.z);  a.w = fmaf(v3, WCUR[0].w, a.w); \
            a.x = fmaf(v1, WCUR[1].x, a.x);  a.y = fmaf(v2, WCUR[1].y, a.y); \
            a.z = fmaf(v3, WCUR[1].z, a.z);  a.w = fmaf(v4, WCUR[1].w, a.w); \
            a.x = fmaf(v2, WCUR[2].x, a.x);  a.y = fmaf(v3, WCUR[2].y, a.y); \
            a.z = fmaf(v4, WCUR[2].z, a.z);  a.w = fmaf(v5, WCUR[2].w, a.w); \
            a.x = fmaf(v3, WCUR[3].x, a.x);  a.y = fmaf(v4, WCUR[3].y, a.y); \
            a.z = fmaf(v5, WCUR[3].z, a.z);  a.w = fmaf(v6, WCUR[3].w, a.w); \
            a.x = fmaf(v4, WCUR[4].x, a.x);  a.y = fmaf(v5, WCUR[4].y, a.y); \
            a.z = fmaf(v6, WCUR[4].z, a.z);  a.w = fmaf(v7, WCUR[4].w, a.w); \
            a.x = fmaf(v5, WCUR[5].x, a.x);  a.y = fmaf(v6, WCUR[5].y, a.y); \
            a.z = fmaf(v7, WCUR[5].z, a.z);  a.w = fmaf(v8, WCUR[5].w, a.w); \
            a.x = fmaf(v6, WCUR[6].x, a.x);  a.y = fmaf(v7, WCUR[6].y, a.y); \
            a.z = fmaf(v8, WCUR[6].z, a.z);  a.w = fmaf(v9, WCUR[6].w, a.w); \
            acc[ch] = a;                                                    \
        }                                                                   \
    }

    KH_STEP(0, wka, wkb, 1, true)
    KH_STEP(1, wkb, wka, 2, true)
    KH_STEP(2, wka, wkb, 3, true)
    KH_STEP(3, wkb, wka, 4, true)
    KH_STEP(4, wka, wkb, 5, true)
    KH_STEP(5, wkb, wka, 6, true)
    KH_STEP(6, wka, wkb, 0, false)
#undef KH_STEP

    // ---- store 4 channels x 4 pixels ----
#pragma unroll
    for (int ch = 0; ch < CHPC; ++ch)
        *(float4*)(og + (size_t)ch * HW) = acc[ch];
}

extern "C" void kernel_launch(void* const* d_in, const int* in_sizes, int n_in,
                              void* d_out, int out_size, void* d_ws, size_t ws_size,
                              hipStream_t stream) {
    const float* x = (const float*)d_in[0];
    const float* w = (const float*)d_in[1];
    float* out = (float*)d_out;

    dim3 grid((HH / TILE_ROWS) * CSPLIT * GG * BB);   // 4096 blocks, 1D for swizzle
    dim3 block(256);
    involution_kernel<<<grid, block, 0, stream>>>(x, w, out);
}